// Round 7
// baseline (8898.864 us; speedup 1.0000x reference)
//
#include <hip/hip_runtime.h>

// LSTM LM: S=512, B=32, H=D=1024, L=2 (fp32 tensors; bf16 MFMA compute).
// Persistent 2-team pipeline (A=layer0 blocks 0-127, B=layer1 blocks 128-255).
// Round-9 = round-8 (barrier-free wave-autonomous steps) + BOUNDED POLLS:
//  a poll that exceeds ~4M iterations (~0.3s, >>10^5 x normal wait) marks the
//  thread dead and short-circuits all later polls -> a deadlock terminates
//  with wrong output instead of wedging the container (diagnosable).
//  Structure recap:
//  - wave (m,n) = 16 batches x 16 gate-cols, full K=2048 in-wave => no
//    cross-wave reduction, NO __syncthreads in the 512-step loop.
//  - ring h published/read via sc0 sc1 (MALL) ops; per-wave flag after
//    own-wave drain; consumers poll the 256-flag m-region of their producers.
//  - asm-staged fragments capped at 32 live (128 VGPR): avoids array->scratch
//    demotion, which races asm global_load outputs (round-5 NaN cause).
//  - counted vmcnt: before consuming group G, WVC(N) with N <= #vmem ops
//    issued after G (invisible compiler ops only tighten the wait).

typedef __bf16 bf16x8 __attribute__((ext_vector_type(8)));
typedef float f32x4 __attribute__((ext_vector_type(4)));
typedef unsigned int u32x4 __attribute__((ext_vector_type(4)));

#define NSTEPS 512
#define TEAM   128
#define OUT_ELEMS 16777216   // 512*32*1024 fp32 outputs
#define BH 32768             // 32*1024
#define POLL_LIMIT (1u << 22)

// LDS: wfrag 131072 | scw 4 waves x 272 f32 = 4352
#define LDS_BYTES 135424
#define OFF_SC   131072

__device__ __forceinline__ unsigned short f2b(float f) {
    unsigned int u = __float_as_uint(f);
    u += 0x7fffu + ((u >> 16) & 1u);   // RNE
    return (unsigned short)(u >> 16);
}
__device__ __forceinline__ float sigm(float x) { return 1.0f / (1.0f + __expf(-x)); }

__device__ __forceinline__ bf16x8 cvt8(const float* p) {
    float4 a = *(const float4*)p;
    float4 b = *(const float4*)(p + 4);
    bf16x8 r;
    r[0] = (__bf16)a.x; r[1] = (__bf16)a.y; r[2] = (__bf16)a.z; r[3] = (__bf16)a.w;
    r[4] = (__bf16)b.x; r[5] = (__bf16)b.y; r[6] = (__bf16)b.z; r[7] = (__bf16)b.w;
    return r;
}

// ---- MALL (coherence-point) access primitives ----
__device__ __forceinline__ bf16x8 ld16(const unsigned short* p) {
    u32x4 r;
    asm volatile("global_load_dwordx4 %0, %1, off sc0 sc1" : "=v"(r) : "v"(p));
    return __builtin_bit_cast(bf16x8, r);
}
__device__ __forceinline__ void st2_mall(unsigned short* p, unsigned int v) {
    asm volatile("global_store_short %0, %1, off sc0 sc1" :: "v"(p), "v"(v) : "memory");
}
// counted vmem wait + scheduler fence (register-only MFMA would otherwise be
// scheduled across the asm wait despite the memory clobber)
#define WVC(N) do { asm volatile("s_waitcnt vmcnt(" #N ")" ::: "memory"); \
                    __builtin_amdgcn_sched_barrier(0); } while (0)

__device__ __forceinline__ unsigned int flag_ld(const unsigned int* p) {
    return __hip_atomic_load(p, __ATOMIC_RELAXED, __HIP_MEMORY_SCOPE_AGENT);
}
__device__ __forceinline__ void flag_st(unsigned int* p, unsigned int v) {
    __hip_atomic_store(p, v, __ATOMIC_RELAXED, __HIP_MEMORY_SCOPE_AGENT);
}
// wave polls a 256-dword flag region (4 per lane); bounded: on timeout clears
// *alive so all later polls return immediately (deadlock -> fast garbage exit)
__device__ __forceinline__ void poll4(const unsigned int* f, int lane,
                                      unsigned int tgt, int* alive) {
    if (!*alive) return;
    unsigned int it = 0;
    for (;;) {
        unsigned int a = flag_ld(f + lane);
        unsigned int b = flag_ld(f + 64 + lane);
        unsigned int c = flag_ld(f + 128 + lane);
        unsigned int d = flag_ld(f + 192 + lane);
        if (a >= tgt && b >= tgt && c >= tgt && d >= tgt) break;
        if (++it > POLL_LIMIT) { *alive = 0; break; }
        __builtin_amdgcn_s_sleep(1);
    }
    asm volatile("" ::: "memory");
}

#define MM(aop, ck) acc = __builtin_amdgcn_mfma_f32_16x16x32_bf16((aop), wfv[(ck) * 64 + lane], acc, 0, 0, 0)

extern "C" __global__ __launch_bounds__(256, 1)
void lstm_persist(const int* __restrict__ tokens,
                  const float* __restrict__ h0in,
                  const float* __restrict__ c0in,
                  const float* __restrict__ emb,
                  const float* __restrict__ Wih0,
                  const float* __restrict__ Whh0,
                  const float* __restrict__ bih0,
                  const float* __restrict__ bhh0,
                  const float* __restrict__ Wih1,
                  const float* __restrict__ Whh1,
                  const float* __restrict__ bih1,
                  const float* __restrict__ bhh1,
                  float* __restrict__ dout,
                  unsigned short* __restrict__ h0b,   // ring: R x BH bf16
                  unsigned short* __restrict__ h1b,   // ring: R x BH bf16
                  unsigned int* __restrict__ cnt,     // flags: 2 teams x 512
                  int R)
{
    extern __shared__ char smem[];
    unsigned short* wfrag = (unsigned short*)smem;
    const bf16x8* wfv = (const bf16x8*)smem;
    float* scAll = (float*)(smem + OFF_SC);

    const int tid  = threadIdx.x;
    const int w    = tid >> 6;
    const int lane = tid & 63;
    const int lm   = lane & 15;
    const int lq   = lane >> 4;
    const int m    = w & 1;          // batch half (rows m*16..m*16+15)
    const int n    = w >> 1;         // col half (16 of block's 32 gate-cols)
    const int blk  = blockIdx.x;
    const bool tB  = (blk >= TEAM);
    const int bid  = tB ? blk - TEAM : blk;
    const int n0   = bid * 8;
    const int b16  = lane >> 2;      // epilogue batch within half
    const int u    = lane & 3;       // epilogue unit within wave's 4

    const float* preW = tB ? Whh1 : Wih0;   // K-steps 0..31
    const float* strW = tB ? Wih1 : Whh0;   // K-steps 32..63
    const float* bi   = tB ? bih1 : bih0;
    const float* bh_  = tB ? bhh1 : bhh0;
    unsigned int* flagT = cnt + (tB ? 512 : 0);
    unsigned int* flagO = cnt + (tB ? 0 : 512);
    unsigned int* myflag = flagT + m * 256 + n * 128 + bid;
    const unsigned int* ownQ = flagT + m * 256;
    const unsigned int* othQ = flagO + m * 256;
    unsigned short* myring = tB ? h1b : h0b;

    const int uoff   = n0 + n * 4 + u;                 // this lane's unit
    const int rowOff = (m * 16 + b16) * 1024 + uoff;   // within one BH slab
    const int loff   = tB ? BH : 0;

    // ---- init: h -> ring slot R-1 (write-through); c + bias in registers ----
    st2_mall(myring + (size_t)(R - 1) * BH + rowOff, (unsigned int)f2b(h0in[loff + rowOff]));
    float cReg  = c0in[loff + rowOff];
    float bias0 = bi[0 * 1024 + uoff] + bh_[0 * 1024 + uoff];
    float bias1 = bi[1 * 1024 + uoff] + bh_[1 * 1024 + uoff];
    float bias2 = bi[2 * 1024 + uoff] + bh_[2 * 1024 + uoff];
    float bias3 = bi[3 * 1024 + uoff] + bh_[3 * 1024 + uoff];

    // ---- weights fp32->bf16 into frag-ordered LDS ----
    // chunk = cn*64 + ks (ks 0..31 = preW, 32..63 = strW); 16 cols = {i,f,g,o}x4u
    for (int t = tid; t < 8192; t += 256) {
        int chunk = t >> 6; int l = t & 63;
        int cn = chunk >> 6; int ks = chunk & 63;
        int lmc = l & 15, lq2 = l >> 4;
        int g = lmc >> 2, uu = lmc & 3;
        int grow = g * 1024 + n0 + cn * 4 + uu;
        const float* W = (ks < 32) ? preW : strW;
        *(bf16x8*)(wfrag + chunk * 512 + l * 8) = cvt8(W + (size_t)grow * 1024 + (ks & 31) * 32 + lq2 * 8);
    }
    asm volatile("s_waitcnt vmcnt(0)" ::: "memory");
    __syncthreads();
    if (lane == 0) flag_st(myflag, 1u);   // flag==k => step k-2 published

    float* scw = scAll + w * 272;                 // padded per-wave exchange
    const int sidx = lane * 4 + lq * 4;           // = lq*68 + lm*4 (16B aligned)
    const int radd = lq * 4 + (b16 & 3);

    int alive = 1;
    f32x4 acc;
    const f32x4 zero = {0.f, 0.f, 0.f, 0.f};

    for (int s = 0; s < NSTEPS; ++s) {
        const int slotPrev = (s + R - 1) % R;
        const int slotCur  = s % R;
        acc = zero;

        if (!tB) {
            // ---- layer0: emb half (K 0..31, Wih0) — off the recurrence ----
            const int tok = tokens[s * 32 + m * 16 + lm];
            const float* er = emb + (size_t)tok * 1024 + lq * 8;
            #pragma unroll
            for (int gp = 0; gp < 4; ++gp) {
                bf16x8 ef[8];
                #pragma unroll
                for (int j = 0; j < 8; ++j) ef[j] = cvt8(er + (gp * 8 + j) * 32);
                #pragma unroll
                for (int j = 0; j < 8; ++j) MM(ef[j], n * 64 + gp * 8 + j);
            }
            poll4(ownQ, lane, (unsigned int)(s + 1), &alive);         // h0[s-1] ready
            if (s >= R) poll4(othQ, lane, (unsigned int)(s - R + 2), &alive); // overwrite ok
            const unsigned short* hr = h0b + (size_t)slotPrev * BH + (m * 16 + lm) * 1024 + lq * 8;
            bf16x8 s0[16], s1[16];
            #pragma unroll
            for (int kk = 0; kk < 16; ++kk) s0[kk] = ld16(hr + kk * 32);
            #pragma unroll
            for (int kk = 0; kk < 16; ++kk) s1[kk] = ld16(hr + (16 + kk) * 32);
            WVC(16);   // s0 resident (newest 16 = s1)
            #pragma unroll
            for (int kk = 0; kk < 16; ++kk) MM(s0[kk], n * 64 + 32 + kk);
            WVC(0);    // s1 resident
            #pragma unroll
            for (int kk = 0; kk < 16; ++kk) MM(s1[kk], n * 64 + 48 + kk);
        } else {
            // ---- layer1: h1[s-1] (Whh1) then h0[s] (Wih1), 4x16 pipeline ----
            poll4(ownQ, lane, (unsigned int)(s + 1), &alive);         // h1[s-1] ready
            const unsigned short* pr = h1b + (size_t)slotPrev * BH + (m * 16 + lm) * 1024 + lq * 8;
            bf16x8 p0[16], p1[16];
            #pragma unroll
            for (int kk = 0; kk < 16; ++kk) p0[kk] = ld16(pr + kk * 32);
            #pragma unroll
            for (int kk = 0; kk < 16; ++kk) p1[kk] = ld16(pr + (16 + kk) * 32);
            poll4(othQ, lane, (unsigned int)(s + 2), &alive);         // h0[s] published
            const unsigned short* hr = h0b + (size_t)slotCur * BH + (m * 16 + lm) * 1024 + lq * 8;
            WVC(16);   // p0 resident (newest 16 <= p1)
            #pragma unroll
            for (int kk = 0; kk < 16; ++kk) MM(p0[kk], n * 64 + kk);
            bf16x8 s0[16];
            #pragma unroll
            for (int kk = 0; kk < 16; ++kk) s0[kk] = ld16(hr + kk * 32);
            WVC(16);   // p1 resident (newest 16 = s0)
            #pragma unroll
            for (int kk = 0; kk < 16; ++kk) MM(p1[kk], n * 64 + 16 + kk);
            bf16x8 s1[16];
            #pragma unroll
            for (int kk = 0; kk < 16; ++kk) s1[kk] = ld16(hr + (16 + kk) * 32);
            WVC(16);   // s0 resident (newest 16 = s1)
            #pragma unroll
            for (int kk = 0; kk < 16; ++kk) MM(s0[kk], n * 64 + 32 + kk);
            WVC(0);    // s1 resident
            #pragma unroll
            for (int kk = 0; kk < 16; ++kk) MM(s1[kk], n * 64 + 48 + kk);
        }

        // ---- per-wave epilogue: in-wave gate exchange, NO block barrier ----
        *(f32x4*)(scw + sidx) = acc;
        asm volatile("s_waitcnt lgkmcnt(0)" ::: "memory");
        __builtin_amdgcn_sched_barrier(0);
        float G0 = scw[(lq * 16 + 0 + u) * 4 + radd] + bias0;
        float G1 = scw[(lq * 16 + 4 + u) * 4 + radd] + bias1;
        float G2 = scw[(lq * 16 + 8 + u) * 4 + radd] + bias2;
        float G3 = scw[(lq * 16 + 12 + u) * 4 + radd] + bias3;
        float ig = sigm(G0);
        float fg = sigm(G1);
        float gg = tanhf(G2);
        float og = sigm(G3);
        float cN = fg * cReg + ig * gg;
        float hN = og * tanhf(cN);
        cReg = cN;

        st2_mall(myring + (size_t)slotCur * BH + rowOff, (unsigned int)f2b(hN));
        WVC(0);                       // publish drained to MALL
        if (lane == 0) flag_st(myflag, (unsigned int)(s + 2));

        if (tB) {
            dout[(size_t)s * BH + rowOff] = hN;                       // outputs [S,B,H]
            if (s == NSTEPS - 1) {
                dout[OUT_ELEMS + BH + rowOff] = hN;                   // hF layer1
                dout[OUT_ELEMS + 3 * BH + rowOff] = cN;               // cF layer1
            }
        } else if (s == NSTEPS - 1) {
            dout[OUT_ELEMS + rowOff] = hN;                            // hF layer0
            dout[OUT_ELEMS + 2 * BH + rowOff] = cN;                   // cF layer0
        }
    }
}

extern "C" void kernel_launch(void* const* d_in, const int* in_sizes, int n_in,
                              void* d_out, int out_size, void* d_ws, size_t ws_size,
                              hipStream_t stream) {
    hipFuncSetAttribute((const void*)lstm_persist,
                        hipFuncAttributeMaxDynamicSharedMemorySize, LDS_BYTES);
    hipMemsetAsync(d_ws, 0, 4096, stream);   // flags: 2 teams x 512 dwords

    const int* tokens = (const int*)d_in[0];
    const float* h0   = (const float*)d_in[1];
    const float* c0   = (const float*)d_in[2];
    const float* emb  = (const float*)d_in[3];
    const float* Wih0 = (const float*)d_in[4];
    const float* Whh0 = (const float*)d_in[5];
    const float* bih0 = (const float*)d_in[6];
    const float* bhh0 = (const float*)d_in[7];
    const float* Wih1 = (const float*)d_in[8];
    const float* Whh1 = (const float*)d_in[9];
    const float* bih1 = (const float*)d_in[10];
    const float* bhh1 = (const float*)d_in[11];

    long long avail = (long long)ws_size - 4096;
    long long r = avail / (2LL * BH * 2);
    int R = (int)(r > NSTEPS ? NSTEPS : r);
    if (R < 2) R = 2;

    unsigned int* cnt = (unsigned int*)d_ws;
    unsigned short* h0b = (unsigned short*)((char*)d_ws + 4096);
    unsigned short* h1b = h0b + (size_t)R * BH;

    lstm_persist<<<dim3(256), dim3(256), LDS_BYTES, stream>>>(
        tokens, h0, c0, emb, Wih0, Whh0, bih0, bhh0, Wih1, Whh1, bih1, bhh1,
        (float*)d_out, h0b, h1b, cnt, R);
}

// Round 8
// 7797.050 us; speedup vs baseline: 1.1413x; 1.1413x over previous
//
#include <hip/hip_runtime.h>

// LSTM LM: S=512, B=32, H=D=1024, L=2 (fp32 tensors; bf16 MFMA compute).
// Persistent 2-team pipeline (A=layer0 blocks 0-127, B=layer1 blocks 128-255),
// weights LDS-resident. Round-10: L2-SHARED h exchange.
//  Evidence (R2-R7): sc0sc1 MALL read path saturates at ~2.7 TB/s aggregate
//  (7.3 GB/s/CU): 24MB/step=8.8us (R2-4), 48MB/step=17.4us (R7). All 128
//  blocks/team re-read the same 64KB h via MALL => 125x redundancy.
//  Fix: consumers use PLAIN CACHED loads preceded by `buffer_inv sc0 sc1`
//  (the gfx94x agent-acquire primitive: invalidates L1 + local-XCD L2 clean
//  lines). Producer side is already the matching release (sc0sc1 stores
//  drained to MALL before the flag). Staleness-safety: any L2 line serving a
//  post-inv read was fetched after a same-XCD poll of the current step =>
//  after the producer's MALL drain => fresh; prior-epoch lines cannot survive
//  16 blocks x R steps of invs. Per-XCD: ~1 MALL fetch/line instead of 16.
//  Base: round-2 verified sync (dual-wave poll phase, 3 barriers/step,
//  pad-36 sc reduce, staged 16B publish + own-wave drain + flag).
//  Bounded polls (anti-wedge): timeout marks thread dead, later polls no-op.

typedef __bf16 bf16x8 __attribute__((ext_vector_type(8)));
typedef float f32x4 __attribute__((ext_vector_type(4)));
typedef unsigned int u32x4 __attribute__((ext_vector_type(4)));

#define NSTEPS 512
#define TEAM   128
#define OUT_ELEMS 16777216   // 512*32*1024 fp32 outputs
#define BH 32768             // 32*1024
#define POLL_LIMIT (1u << 22)

// LDS: wfrag 131072 | sc 18432 (128 x 36 f32) | bias 128 | cst 1024 | hst 512
#define LDS_BYTES 151168
#define OFF_SC   131072
#define OFF_BIAS 149504
#define OFF_CST  149632
#define OFF_HST  150656

__device__ __forceinline__ unsigned short f2b(float f) {
    unsigned int u = __float_as_uint(f);
    u += 0x7fffu + ((u >> 16) & 1u);   // RNE
    return (unsigned short)(u >> 16);
}
__device__ __forceinline__ float sigm(float x) { return 1.0f / (1.0f + __expf(-x)); }

__device__ __forceinline__ bf16x8 cvt8(const float* p) {
    float4 a = *(const float4*)p;
    float4 b = *(const float4*)(p + 4);
    bf16x8 r;
    r[0] = (__bf16)a.x; r[1] = (__bf16)a.y; r[2] = (__bf16)a.z; r[3] = (__bf16)a.w;
    r[4] = (__bf16)b.x; r[5] = (__bf16)b.y; r[6] = (__bf16)b.z; r[7] = (__bf16)b.w;
    return r;
}

// ---- publish-side (MALL write-through) primitives ----
__device__ __forceinline__ void st_mall16(unsigned short* p, u32x4 v) {
    asm volatile("global_store_dwordx4 %0, %1, off sc0 sc1" :: "v"(p), "v"(v) : "memory");
}
__device__ __forceinline__ void st_mall2(unsigned short* p, unsigned int v) {
    asm volatile("global_store_short %0, %1, off sc0 sc1" :: "v"(p), "v"(v) : "memory");
}
__device__ __forceinline__ void wait_vm0() {
    asm volatile("s_waitcnt vmcnt(0)" ::: "memory");
}
// ---- consume-side acquire: invalidate L1 + local-XCD L2 (clean lines) ----
__device__ __forceinline__ void inv_caches() {
    asm volatile("buffer_inv sc0 sc1" ::: "memory");
    __builtin_amdgcn_sched_barrier(0);
}

__device__ __forceinline__ unsigned int flag_ld(const unsigned int* p) {
    return __hip_atomic_load(p, __ATOMIC_RELAXED, __HIP_MEMORY_SCOPE_AGENT);
}
__device__ __forceinline__ void flag_st(unsigned int* p, unsigned int v) {
    __hip_atomic_store(p, v, __ATOMIC_RELAXED, __HIP_MEMORY_SCOPE_AGENT);
}
// one wave covers 128 flags (lane handles f[lane], f[64+lane]); bounded
__device__ __forceinline__ void poll2(const unsigned int* f, int lane,
                                      unsigned int tgt, int* alive) {
    if (!*alive) return;
    unsigned int it = 0;
    while (flag_ld(f + lane) < tgt || flag_ld(f + 64 + lane) < tgt) {
        if (++it > POLL_LIMIT) { *alive = 0; break; }
        __builtin_amdgcn_s_sleep(1);
    }
    asm volatile("" ::: "memory");
}

extern "C" __global__ __launch_bounds__(256, 1)
void lstm_persist(const int* __restrict__ tokens,
                  const float* __restrict__ h0in,
                  const float* __restrict__ c0in,
                  const float* __restrict__ emb,
                  const float* __restrict__ Wih0,
                  const float* __restrict__ Whh0,
                  const float* __restrict__ bih0,
                  const float* __restrict__ bhh0,
                  const float* __restrict__ Wih1,
                  const float* __restrict__ Whh1,
                  const float* __restrict__ bih1,
                  const float* __restrict__ bhh1,
                  float* __restrict__ dout,
                  unsigned short* __restrict__ h0b,   // ring: R x BH bf16
                  unsigned short* __restrict__ h1b,   // ring: R x BH bf16
                  unsigned int* __restrict__ cnt,     // flagA[128], flagB[128]
                  int R)
{
    extern __shared__ char smem[];
    unsigned short* wfrag = (unsigned short*)smem;
    float* sc   = (float*)(smem + OFF_SC);
    float* bias = (float*)(smem + OFF_BIAS);
    float* cst  = (float*)(smem + OFF_CST);
    unsigned short* hst = (unsigned short*)(smem + OFF_HST);

    const int tid  = threadIdx.x;
    const int w    = tid >> 6;        // wave = K-quarter
    const int lane = tid & 63;
    const int lm   = lane & 15;
    const int lq   = lane >> 4;
    const int blk  = blockIdx.x;
    const bool tB  = (blk >= TEAM);   // teamB = layer 1
    const int bid  = tB ? blk - TEAM : blk;
    const int n0   = bid * 8;         // owned hidden units [n0, n0+8)

    const float* Wih = tB ? Wih1 : Wih0;
    const float* Whh = tB ? Whh1 : Whh0;
    const float* bi  = tB ? bih1 : bih0;
    const float* bh  = tB ? bhh1 : bhh0;
    unsigned int* flagA = cnt;
    unsigned int* flagB = cnt + TEAM;
    unsigned int* myflag = (tB ? flagB : flagA) + bid;

    // ---- initial h for OWN production region -> ring slot R-1 (write-through) ----
    {
        int u = tid & 7, b = tid >> 3;
        int loff = tB ? BH : 0;
        unsigned short v = f2b(h0in[loff + b * 1024 + n0 + u]);
        st_mall2((tB ? h1b : h0b) + (size_t)(R - 1) * BH + b * 1024 + n0 + u, (unsigned int)v);
    }

    // ---- convert owned weight columns fp32->bf16 into frag-ordered LDS ----
    // chunk = (mat*2+nt)*32+ks ; lane holds W[col nt*16+n][ks*32 + q*8 .. +7]
    for (int t = tid; t < 8192; t += 256) {
        int chunk = t >> 6; int l = t & 63;
        int mat = chunk >> 6; int rem = chunk & 63;
        int nt = rem >> 5; int ks = rem & 31;
        int n = l & 15, q = l >> 4;
        int cl = nt * 16 + n;
        int grow = (cl >> 3) * 1024 + n0 + (cl & 7);
        const float* src = (mat ? Whh : Wih) + (size_t)grow * 1024 + ks * 32 + q * 8;
        *(bf16x8*)(wfrag + chunk * 512 + l * 8) = cvt8(src);
    }
    if (tid < 32) {
        int grow = (tid >> 3) * 1024 + n0 + (tid & 7);
        bias[tid] = bi[grow] + bh[grow];
    }
    {   // fp32 cell state, block-resident
        int u = tid & 7, b = tid >> 3;
        int loff = tB ? BH : 0;
        cst[b * 8 + u] = c0in[loff + b * 1024 + n0 + u];
    }
    wait_vm0();          // drain asm init stores (outside compiler bookkeeping)
    __syncthreads();
    if (tid == 0) flag_st(myflag, 1u);   // flag==k  =>  h[k-2] published

    int alive = 1;
    f32x4 acc[2][2];
    bf16x8 pre[2][8];
    bf16x8 sa[2][8];
    const f32x4 zero = {0.f, 0.f, 0.f, 0.f};

    for (int s = 0; s < NSTEPS; ++s) {
        const int slotPrev = (s + R - 1) % R;
        const int slotCur  = s % R;
        const unsigned short* hs;   // stream source (cached post-inv)
        int preMat, strMat;

        if (!tB) {
            // ---- team A: emb gather (cached) while deps resolve ----
            #pragma unroll
            for (int mt = 0; mt < 2; ++mt) {
                const float* rowp = emb + (size_t)tokens[s * 32 + mt * 16 + lm] * 1024 + lq * 8;
                #pragma unroll
                for (int i = 0; i < 8; ++i)
                    pre[mt][i] = cvt8(rowp + (w * 8 + i) * 32);
            }
            // w0: A peers done s-1 ; w1: back-pressure vs B at distance R
            if (w == 0)                poll2(flagA, lane, (unsigned int)(s + 1), &alive);
            else if (w == 1 && s >= R) poll2(flagB, lane, (unsigned int)(s - R + 2), &alive);
            __syncthreads();
            inv_caches();                     // acquire: drop stale L1/L2 lines
            hs = h0b + (size_t)slotPrev * BH;  preMat = 0; strMat = 1;
            #pragma unroll
            for (int mt = 0; mt < 2; ++mt)
                #pragma unroll
                for (int i = 0; i < 8; ++i)
                    sa[mt][i] = *(const bf16x8*)(hs + (mt * 16 + lm) * 1024 + (w * 8 + i) * 32 + lq * 8);
        } else {
            // ---- team B: both deps polled concurrently, one barrier ----
            if (w == 0)      poll2(flagB, lane, (unsigned int)(s + 1), &alive);
            else if (w == 1) poll2(flagA, lane, (unsigned int)(s + 2), &alive);
            __syncthreads();
            inv_caches();                     // acquire for BOTH h1 and h0 reads
            const unsigned short* h1src = h1b + (size_t)slotPrev * BH;
            #pragma unroll
            for (int mt = 0; mt < 2; ++mt)
                #pragma unroll
                for (int i = 0; i < 8; ++i)
                    pre[mt][i] = *(const bf16x8*)(h1src + (mt * 16 + lm) * 1024 + (w * 8 + i) * 32 + lq * 8);
            hs = h0b + (size_t)slotCur * BH;  preMat = 1; strMat = 0;
            #pragma unroll
            for (int mt = 0; mt < 2; ++mt)
                #pragma unroll
                for (int i = 0; i < 8; ++i)
                    sa[mt][i] = *(const bf16x8*)(hs + (mt * 16 + lm) * 1024 + (w * 8 + i) * 32 + lq * 8);
        }

        acc[0][0] = zero; acc[0][1] = zero; acc[1][0] = zero; acc[1][1] = zero;

        // ---- pre half ----
        #pragma unroll
        for (int i = 0; i < 8; ++i) {
            int ks = w * 8 + i;
            bf16x8 bp0 = *(const bf16x8*)(wfrag + ((preMat * 2 + 0) * 32 + ks) * 512 + lane * 8);
            bf16x8 bp1 = *(const bf16x8*)(wfrag + ((preMat * 2 + 1) * 32 + ks) * 512 + lane * 8);
            acc[0][0] = __builtin_amdgcn_mfma_f32_16x16x32_bf16(pre[0][i], bp0, acc[0][0], 0, 0, 0);
            acc[0][1] = __builtin_amdgcn_mfma_f32_16x16x32_bf16(pre[0][i], bp1, acc[0][1], 0, 0, 0);
            acc[1][0] = __builtin_amdgcn_mfma_f32_16x16x32_bf16(pre[1][i], bp0, acc[1][0], 0, 0, 0);
            acc[1][1] = __builtin_amdgcn_mfma_f32_16x16x32_bf16(pre[1][i], bp1, acc[1][1], 0, 0, 0);
        }
        // ---- stream half ----
        #pragma unroll
        for (int i = 0; i < 8; ++i) {
            int ks = w * 8 + i;
            bf16x8 bs0 = *(const bf16x8*)(wfrag + ((strMat * 2 + 0) * 32 + ks) * 512 + lane * 8);
            bf16x8 bs1 = *(const bf16x8*)(wfrag + ((strMat * 2 + 1) * 32 + ks) * 512 + lane * 8);
            acc[0][0] = __builtin_amdgcn_mfma_f32_16x16x32_bf16(sa[0][i], bs0, acc[0][0], 0, 0, 0);
            acc[0][1] = __builtin_amdgcn_mfma_f32_16x16x32_bf16(sa[0][i], bs1, acc[0][1], 0, 0, 0);
            acc[1][0] = __builtin_amdgcn_mfma_f32_16x16x32_bf16(sa[1][i], bs0, acc[1][0], 0, 0, 0);
            acc[1][1] = __builtin_amdgcn_mfma_f32_16x16x32_bf16(sa[1][i], bs1, acc[1][1], 0, 0, 0);
        }

        // cross-wave K reduction via padded LDS (C layout: col=lane&15, row=quad*4+reg)
        // pad 36: write 2-way, epilogue read bank=(4b+u)%32 -> 2-way (free)
        #pragma unroll
        for (int mt = 0; mt < 2; ++mt) {
            #pragma unroll
            for (int nt = 0; nt < 2; ++nt) {
                f32x4 a = acc[mt][nt];
                int col = nt * 16 + lm;
                int rb = w * 32 + mt * 16 + lq * 4;
                sc[(rb + 0) * 36 + col] = a[0];
                sc[(rb + 1) * 36 + col] = a[1];
                sc[(rb + 2) * 36 + col] = a[2];
                sc[(rb + 3) * 36 + col] = a[3];
            }
        }
        __syncthreads();

        // epilogue: gates -> (h,c) for owned 8 units x 32 batch
        {
            int u = tid & 7, b = tid >> 3;
            float G[4];
            #pragma unroll
            for (int g = 0; g < 4; ++g) {
                int col = g * 8 + u;
                float v = bias[col];
                #pragma unroll
                for (int w2 = 0; w2 < 4; ++w2) v += sc[(w2 * 32 + b) * 36 + col];
                G[g] = v;
            }
            float ig = sigm(G[0]);
            float fg = sigm(G[1]);
            float gg = tanhf(G[2]);
            float og = sigm(G[3]);
            float cOld = cst[b * 8 + u];
            float cNew = fg * cOld + ig * gg;
            float hNew = og * tanhf(cNew);
            cst[b * 8 + u] = cNew;
            hst[b * 8 + u] = f2b(hNew);
            __syncthreads();

            // wave0 publishes the whole 32x8 slice as 32 x 16B MALL stores,
            // drains own wave, flags. dout stores after the flag.
            if (tid < 32) {
                u32x4 v16 = *(const u32x4*)(hst + tid * 8);
                unsigned short* dst = (tB ? h1b : h0b) + (size_t)slotCur * BH + tid * 1024 + n0;
                st_mall16(dst, v16);
            }
            if (w == 0) {
                wait_vm0();
                if (tid == 0) flag_st(myflag, (unsigned int)(s + 2));
            }

            int off = b * 1024 + n0 + u;
            if (tB) {
                dout[(size_t)s * BH + off] = hNew;             // outputs [S,B,H]
                if (s == NSTEPS - 1) {
                    dout[OUT_ELEMS + BH + off] = hNew;         // hF layer1
                    dout[OUT_ELEMS + 3 * BH + off] = cNew;     // cF layer1
                }
            } else if (s == NSTEPS - 1) {
                dout[OUT_ELEMS + off] = hNew;                  // hF layer0
                dout[OUT_ELEMS + 2 * BH + off] = cNew;         // cF layer0
            }
        }
    }
}

extern "C" void kernel_launch(void* const* d_in, const int* in_sizes, int n_in,
                              void* d_out, int out_size, void* d_ws, size_t ws_size,
                              hipStream_t stream) {
    hipFuncSetAttribute((const void*)lstm_persist,
                        hipFuncAttributeMaxDynamicSharedMemorySize, LDS_BYTES);
    hipMemsetAsync(d_ws, 0, 4096, stream);   // flagA[128] + flagB[128] (+pad)

    const int* tokens = (const int*)d_in[0];
    const float* h0   = (const float*)d_in[1];
    const float* c0   = (const float*)d_in[2];
    const float* emb  = (const float*)d_in[3];
    const float* Wih0 = (const float*)d_in[4];
    const float* Whh0 = (const float*)d_in[5];
    const float* bih0 = (const float*)d_in[6];
    const float* bhh0 = (const float*)d_in[7];
    const float* Wih1 = (const float*)d_in[8];
    const float* Whh1 = (const float*)d_in[9];
    const float* bih1 = (const float*)d_in[10];
    const float* bhh1 = (const float*)d_in[11];

    long long avail = (long long)ws_size - 4096;
    long long r = avail / (2LL * BH * 2);
    int R = (int)(r > NSTEPS ? NSTEPS : r);
    if (R < 2) R = 2;

    unsigned int* cnt = (unsigned int*)d_ws;
    unsigned short* h0b = (unsigned short*)((char*)d_ws + 4096);
    unsigned short* h1b = h0b + (size_t)R * BH;

    lstm_persist<<<dim3(256), dim3(256), LDS_BYTES, stream>>>(
        tokens, h0, c0, emb, Wih0, Whh0, bih0, bhh0, Wih1, Whh1, bih1, bhh1,
        (float*)d_out, h0b, h1b, cnt, R);
}

// Round 9
// 4829.673 us; speedup vs baseline: 1.8425x; 1.6144x over previous
//
#include <hip/hip_runtime.h>

// LSTM LM: S=512, B=32, H=D=1024, L=2 (fp32 tensors; bf16 MFMA compute).
// Persistent 2-team pipeline (A=layer0 blocks 0-127, B=layer1 blocks 128-255),
// weights LDS-resident. Round-11: CACHED consumer reads, eviction-distance safe.
//  Evidence: sc0sc1 MALL read path saturates ~2.7 TB/s (24MB/step=8.8us R2-4,
//  48MB/step=17.4us R7); per-step cache maintenance is disastrous (R8 inv:
//  +3.2us/step). Fix with ZERO maintenance ops: consumers use plain cached
//  loads; ring R>=64 guarantees a slot's address is reused only after
//  R x ~320KB/step >= 20MB (R=64) .. 160MB (R=511) of per-XCD L2 fills
//  through a 4MB L2 => stale lines are evicted long before reuse. Producer
//  sc0sc1 stores never allocate in L2 (only consumer reads do), and first
//  post-flag read per XCD fetches fresh from MALL => the other 15 team blocks
//  hit L2. MALL read traffic 24MB -> ~1.5MB/step.
//  Base: round-4 verified kernel (4365us). Fallback (R<64): exact sc0sc1 path.
//  Bounded polls: timeout marks thread dead => deadlock exits with garbage
//  instead of wedging the container.

typedef __bf16 bf16x8 __attribute__((ext_vector_type(8)));
typedef float f32x4 __attribute__((ext_vector_type(4)));
typedef unsigned int u32x4 __attribute__((ext_vector_type(4)));

#define NSTEPS 512
#define TEAM   128
#define OUT_ELEMS 16777216   // 512*32*1024 fp32 outputs
#define BH 32768             // 32*1024
#define POLL_LIMIT (1u << 22)

// LDS: wfrag 131072 | sc 18432 (128 x 36 f32) | bias 128 | cst 1024 | hst 512
#define LDS_BYTES 151168
#define OFF_SC   131072
#define OFF_BIAS 149504
#define OFF_CST  149632
#define OFF_HST  150656

__device__ __forceinline__ unsigned short f2b(float f) {
    unsigned int u = __float_as_uint(f);
    u += 0x7fffu + ((u >> 16) & 1u);   // RNE
    return (unsigned short)(u >> 16);
}
__device__ __forceinline__ float sigm(float x) { return 1.0f / (1.0f + __expf(-x)); }

__device__ __forceinline__ bf16x8 cvt8(const float* p) {
    float4 a = *(const float4*)p;
    float4 b = *(const float4*)(p + 4);
    bf16x8 r;
    r[0] = (__bf16)a.x; r[1] = (__bf16)a.y; r[2] = (__bf16)a.z; r[3] = (__bf16)a.w;
    r[4] = (__bf16)b.x; r[5] = (__bf16)b.y; r[6] = (__bf16)b.z; r[7] = (__bf16)b.w;
    return r;
}

// ---- MALL primitives (publish side; consume side in fallback mode) ----
__device__ __forceinline__ bf16x8 ld_mall16(const unsigned short* p) {
    u32x4 r;
    asm volatile("global_load_dwordx4 %0, %1, off sc0 sc1" : "=v"(r) : "v"(p));
    return __builtin_bit_cast(bf16x8, r);
}
__device__ __forceinline__ void st_mall16(unsigned short* p, u32x4 v) {
    asm volatile("global_store_dwordx4 %0, %1, off sc0 sc1" :: "v"(p), "v"(v) : "memory");
}
__device__ __forceinline__ void st_mall2(unsigned short* p, unsigned int v) {
    asm volatile("global_store_short %0, %1, off sc0 sc1" :: "v"(p), "v"(v) : "memory");
}
__device__ __forceinline__ void wait_vm0() {
    asm volatile("s_waitcnt vmcnt(0)" ::: "memory");
}
__device__ __forceinline__ void wait_vm16() {
    asm volatile("s_waitcnt vmcnt(16)" ::: "memory");
}
__device__ __forceinline__ unsigned int flag_ld(const unsigned int* p) {
    return __hip_atomic_load(p, __ATOMIC_RELAXED, __HIP_MEMORY_SCOPE_AGENT);
}
__device__ __forceinline__ void flag_st(unsigned int* p, unsigned int v) {
    __hip_atomic_store(p, v, __ATOMIC_RELAXED, __HIP_MEMORY_SCOPE_AGENT);
}
// wave polls 32 flags (one 128B line); lanes 32-63 duplicate lanes 0-31.
// Bounded: on timeout clears *alive; later polls no-op (deadlock -> fast exit).
// Trailing compiler barrier: no load may be hoisted above the poll.
__device__ __forceinline__ void pollq(const unsigned int* f, int l32,
                                      unsigned int tgt, int* alive) {
    if (!*alive) return;
    unsigned int it = 0;
    while (flag_ld(f + l32) < tgt) {
        if (++it > POLL_LIMIT) { *alive = 0; break; }
        __builtin_amdgcn_s_sleep(1);
    }
    asm volatile("" ::: "memory");
}

template<int CACHED>
__device__ __forceinline__ void body(const int* __restrict__ tokens,
                                     const float* __restrict__ h0in,
                                     const float* __restrict__ c0in,
                                     const float* __restrict__ emb,
                                     const float* __restrict__ Wih0,
                                     const float* __restrict__ Whh0,
                                     const float* __restrict__ bih0,
                                     const float* __restrict__ bhh0,
                                     const float* __restrict__ Wih1,
                                     const float* __restrict__ Whh1,
                                     const float* __restrict__ bih1,
                                     const float* __restrict__ bhh1,
                                     float* __restrict__ dout,
                                     unsigned short* __restrict__ h0b,
                                     unsigned short* __restrict__ h1b,
                                     unsigned int* __restrict__ cnt,
                                     int R)
{
    extern __shared__ char smem[];
    unsigned short* wfrag = (unsigned short*)smem;
    float* sc   = (float*)(smem + OFF_SC);
    float* bias = (float*)(smem + OFF_BIAS);
    float* cst  = (float*)(smem + OFF_CST);
    unsigned short* hst = (unsigned short*)(smem + OFF_HST);

    const int tid  = threadIdx.x;
    const int w    = tid >> 6;        // wave = K-quarter
    const int lane = tid & 63;
    const int lm   = lane & 15;
    const int lq   = lane >> 4;
    const int l32  = lane & 31;
    const int blk  = blockIdx.x;
    const bool tB  = (blk >= TEAM);   // teamB = layer 1
    const int bid  = tB ? blk - TEAM : blk;
    const int n0   = bid * 8;         // owned hidden units [n0, n0+8)

    const float* Wih = tB ? Wih1 : Wih0;
    const float* Whh = tB ? Whh1 : Whh0;
    const float* bi  = tB ? bih1 : bih0;
    const float* bh  = tB ? bhh1 : bhh0;
    unsigned int* flagA = cnt;
    unsigned int* flagB = cnt + TEAM;
    unsigned int* myflag = (tB ? flagB : flagA) + bid;
    const unsigned int* ownQ  = (tB ? flagB : flagA) + w * 32;  // own-team quarter
    const unsigned int* othQ  = (tB ? flagA : flagB) + w * 32;  // other-team quarter

    // ---- initial h for OWN production region -> ring slot R-1 (write-through) ----
    {
        int u = tid & 7, b = tid >> 3;
        int loff = tB ? BH : 0;
        unsigned short v = f2b(h0in[loff + b * 1024 + n0 + u]);
        st_mall2((tB ? h1b : h0b) + (size_t)(R - 1) * BH + b * 1024 + n0 + u, (unsigned int)v);
    }

    // ---- convert owned weight columns fp32->bf16 into frag-ordered LDS ----
    for (int t = tid; t < 8192; t += 256) {
        int chunk = t >> 6; int l = t & 63;
        int mat = chunk >> 6; int rem = chunk & 63;
        int nt = rem >> 5; int ks = rem & 31;
        int n = l & 15, q = l >> 4;
        int cl = nt * 16 + n;
        int grow = (cl >> 3) * 1024 + n0 + (cl & 7);
        const float* src = (mat ? Whh : Wih) + (size_t)grow * 1024 + ks * 32 + q * 8;
        *(bf16x8*)(wfrag + chunk * 512 + l * 8) = cvt8(src);
    }
    if (tid < 32) {
        int grow = (tid >> 3) * 1024 + n0 + (tid & 7);
        bias[tid] = bi[grow] + bh[grow];
    }
    {   // fp32 cell state, block-resident
        int u = tid & 7, b = tid >> 3;
        int loff = tB ? BH : 0;
        cst[b * 8 + u] = c0in[loff + b * 1024 + n0 + u];
    }
    wait_vm0();
    __syncthreads();
    if (tid == 0) flag_st(myflag, 1u);   // flag==k  =>  h[k-2] published

    int alive = 1;
    f32x4 acc[2][2];
    bf16x8 pre[2][8];
    bf16x8 sa[2][8];
    const f32x4 zero = {0.f, 0.f, 0.f, 0.f};

    for (int s = 0; s < NSTEPS; ++s) {
        const int slotPrev = (s + R - 1) % R;
        const int slotCur  = s % R;
        const unsigned short* hs;
        int preMat, strMat;

        if (!tB) {
            // ---- team A: emb gather (cached, broadcast token line) ----
            #pragma unroll
            for (int mt = 0; mt < 2; ++mt) {
                const float* rowp = emb + (size_t)tokens[s * 32 + mt * 16 + lm] * 1024 + lq * 8;
                #pragma unroll
                for (int i = 0; i < 8; ++i)
                    pre[mt][i] = cvt8(rowp + (w * 8 + i) * 32);
            }
            pollq(ownQ, l32, (unsigned int)(s + 1), &alive);              // own quarter peers
            if (s >= R) pollq(othQ, l32, (unsigned int)(s - R + 2), &alive); // overwrite ok
            hs = h0b + (size_t)slotPrev * BH;  preMat = 0; strMat = 1;
            if (CACHED) {
                #pragma unroll
                for (int mt = 0; mt < 2; ++mt)
                    #pragma unroll
                    for (int i = 0; i < 8; ++i)
                        sa[mt][i] = *(const bf16x8*)(hs + (mt * 16 + lm) * 1024 + (w * 8 + i) * 32 + lq * 8);
            } else {
                #pragma unroll
                for (int mt = 0; mt < 2; ++mt)
                    #pragma unroll
                    for (int i = 0; i < 8; ++i)
                        sa[mt][i] = ld_mall16(hs + (mt * 16 + lm) * 1024 + (w * 8 + i) * 32 + lq * 8);
            }
        } else {
            // ---- team B: split deps; h1 loads fly during the flagA wait ----
            pollq(ownQ, l32, (unsigned int)(s + 1), &alive);              // B peers done s-1
            const unsigned short* h1src = h1b + (size_t)slotPrev * BH;
            if (CACHED) {
                #pragma unroll
                for (int mt = 0; mt < 2; ++mt)
                    #pragma unroll
                    for (int i = 0; i < 8; ++i)
                        pre[mt][i] = *(const bf16x8*)(h1src + (mt * 16 + lm) * 1024 + (w * 8 + i) * 32 + lq * 8);
            } else {
                #pragma unroll
                for (int mt = 0; mt < 2; ++mt)
                    #pragma unroll
                    for (int i = 0; i < 8; ++i)
                        pre[mt][i] = ld_mall16(h1src + (mt * 16 + lm) * 1024 + (w * 8 + i) * 32 + lq * 8);
            }
            pollq(othQ, l32, (unsigned int)(s + 2), &alive);              // A done step s
            hs = h0b + (size_t)slotCur * BH;  preMat = 1; strMat = 0;
            if (CACHED) {
                #pragma unroll
                for (int mt = 0; mt < 2; ++mt)
                    #pragma unroll
                    for (int i = 0; i < 8; ++i)
                        sa[mt][i] = *(const bf16x8*)(hs + (mt * 16 + lm) * 1024 + (w * 8 + i) * 32 + lq * 8);
            } else {
                #pragma unroll
                for (int mt = 0; mt < 2; ++mt)
                    #pragma unroll
                    for (int i = 0; i < 8; ++i)
                        sa[mt][i] = ld_mall16(hs + (mt * 16 + lm) * 1024 + (w * 8 + i) * 32 + lq * 8);
            }
        }

        acc[0][0] = zero; acc[0][1] = zero; acc[1][0] = zero; acc[1][1] = zero;

        // fallback B: wait only for the 16 pre loads; sa stays in flight
        if (!CACHED && tB) { wait_vm16(); __builtin_amdgcn_sched_barrier(0); }

        // ---- pre half ----
        #pragma unroll
        for (int i = 0; i < 8; ++i) {
            int ks = w * 8 + i;
            bf16x8 bp0 = *(const bf16x8*)(wfrag + ((preMat * 2 + 0) * 32 + ks) * 512 + lane * 8);
            bf16x8 bp1 = *(const bf16x8*)(wfrag + ((preMat * 2 + 1) * 32 + ks) * 512 + lane * 8);
            acc[0][0] = __builtin_amdgcn_mfma_f32_16x16x32_bf16(pre[0][i], bp0, acc[0][0], 0, 0, 0);
            acc[0][1] = __builtin_amdgcn_mfma_f32_16x16x32_bf16(pre[0][i], bp1, acc[0][1], 0, 0, 0);
            acc[1][0] = __builtin_amdgcn_mfma_f32_16x16x32_bf16(pre[1][i], bp0, acc[1][0], 0, 0, 0);
            acc[1][1] = __builtin_amdgcn_mfma_f32_16x16x32_bf16(pre[1][i], bp1, acc[1][1], 0, 0, 0);
        }

        if (!CACHED) { wait_vm0(); __builtin_amdgcn_sched_barrier(0); }

        // ---- stream half ----
        #pragma unroll
        for (int i = 0; i < 8; ++i) {
            int ks = w * 8 + i;
            bf16x8 bs0 = *(const bf16x8*)(wfrag + ((strMat * 2 + 0) * 32 + ks) * 512 + lane * 8);
            bf16x8 bs1 = *(const bf16x8*)(wfrag + ((strMat * 2 + 1) * 32 + ks) * 512 + lane * 8);
            acc[0][0] = __builtin_amdgcn_mfma_f32_16x16x32_bf16(sa[0][i], bs0, acc[0][0], 0, 0, 0);
            acc[0][1] = __builtin_amdgcn_mfma_f32_16x16x32_bf16(sa[0][i], bs1, acc[0][1], 0, 0, 0);
            acc[1][0] = __builtin_amdgcn_mfma_f32_16x16x32_bf16(sa[1][i], bs0, acc[1][0], 0, 0, 0);
            acc[1][1] = __builtin_amdgcn_mfma_f32_16x16x32_bf16(sa[1][i], bs1, acc[1][1], 0, 0, 0);
        }

        // cross-wave K reduction via padded LDS (pad 36: 2-way, free)
        #pragma unroll
        for (int mt = 0; mt < 2; ++mt) {
            #pragma unroll
            for (int nt = 0; nt < 2; ++nt) {
                f32x4 a = acc[mt][nt];
                int col = nt * 16 + lm;
                int rb = w * 32 + mt * 16 + lq * 4;
                sc[(rb + 0) * 36 + col] = a[0];
                sc[(rb + 1) * 36 + col] = a[1];
                sc[(rb + 2) * 36 + col] = a[2];
                sc[(rb + 3) * 36 + col] = a[3];
            }
        }
        __syncthreads();

        // epilogue: gates -> (h,c) for owned 8 units x 32 batch
        {
            int u = tid & 7, b = tid >> 3;
            float G[4];
            #pragma unroll
            for (int g = 0; g < 4; ++g) {
                int col = g * 8 + u;
                float v = bias[col];
                #pragma unroll
                for (int w2 = 0; w2 < 4; ++w2) v += sc[(w2 * 32 + b) * 36 + col];
                G[g] = v;
            }
            float ig = sigm(G[0]);
            float fg = sigm(G[1]);
            float gg = tanhf(G[2]);
            float og = sigm(G[3]);
            float cOld = cst[b * 8 + u];
            float cNew = fg * cOld + ig * gg;
            float hNew = og * tanhf(cNew);
            cst[b * 8 + u] = cNew;
            hst[b * 8 + u] = f2b(hNew);
            __syncthreads();

            // wave0 publishes the 32x8 slice as 32 x 16B MALL stores, drains
            // own wave, flags. dout stores after the flag.
            if (tid < 32) {
                u32x4 v16 = *(const u32x4*)(hst + tid * 8);
                unsigned short* dst = (tB ? h1b : h0b) + (size_t)slotCur * BH + tid * 1024 + n0;
                st_mall16(dst, v16);
            }
            if (w == 0) {
                wait_vm0();
                if (tid == 0) flag_st(myflag, (unsigned int)(s + 2));
            }

            int off = b * 1024 + n0 + u;
            if (tB) {
                dout[(size_t)s * BH + off] = hNew;             // outputs [S,B,H]
                if (s == NSTEPS - 1) {
                    dout[OUT_ELEMS + BH + off] = hNew;         // hF layer1
                    dout[OUT_ELEMS + 3 * BH + off] = cNew;     // cF layer1
                }
            } else if (s == NSTEPS - 1) {
                dout[OUT_ELEMS + off] = hNew;                  // hF layer0
                dout[OUT_ELEMS + 2 * BH + off] = cNew;         // cF layer0
            }
        }
    }
}

extern "C" __global__ __launch_bounds__(256, 1)
void lstm_cached(const int* tokens, const float* h0in, const float* c0in, const float* emb,
                 const float* Wih0, const float* Whh0, const float* bih0, const float* bhh0,
                 const float* Wih1, const float* Whh1, const float* bih1, const float* bhh1,
                 float* dout, unsigned short* h0b, unsigned short* h1b, unsigned int* cnt, int R)
{
    body<1>(tokens, h0in, c0in, emb, Wih0, Whh0, bih0, bhh0,
            Wih1, Whh1, bih1, bhh1, dout, h0b, h1b, cnt, R);
}

extern "C" __global__ __launch_bounds__(256, 1)
void lstm_mall(const int* tokens, const float* h0in, const float* c0in, const float* emb,
               const float* Wih0, const float* Whh0, const float* bih0, const float* bhh0,
               const float* Wih1, const float* Whh1, const float* bih1, const float* bhh1,
               float* dout, unsigned short* h0b, unsigned short* h1b, unsigned int* cnt, int R)
{
    body<0>(tokens, h0in, c0in, emb, Wih0, Whh0, bih0, bhh0,
            Wih1, Whh1, bih1, bhh1, dout, h0b, h1b, cnt, R);
}

extern "C" void kernel_launch(void* const* d_in, const int* in_sizes, int n_in,
                              void* d_out, int out_size, void* d_ws, size_t ws_size,
                              hipStream_t stream) {
    hipFuncSetAttribute((const void*)lstm_cached,
                        hipFuncAttributeMaxDynamicSharedMemorySize, LDS_BYTES);
    hipFuncSetAttribute((const void*)lstm_mall,
                        hipFuncAttributeMaxDynamicSharedMemorySize, LDS_BYTES);
    hipMemsetAsync(d_ws, 0, 4096, stream);   // flagA[128] + flagB[128] (+pad)

    const int* tokens = (const int*)d_in[0];
    const float* h0   = (const float*)d_in[1];
    const float* c0   = (const float*)d_in[2];
    const float* emb  = (const float*)d_in[3];
    const float* Wih0 = (const float*)d_in[4];
    const float* Whh0 = (const float*)d_in[5];
    const float* bih0 = (const float*)d_in[6];
    const float* bhh0 = (const float*)d_in[7];
    const float* Wih1 = (const float*)d_in[8];
    const float* Whh1 = (const float*)d_in[9];
    const float* bih1 = (const float*)d_in[10];
    const float* bhh1 = (const float*)d_in[11];

    // Ring from ws_size. CACHED mode needs R>=64: slot reuse distance then
    // guarantees stale-line eviction (R x ~320KB/step per-XCD L2 turnover
    // >> 4MB L2). Fallback: proven sc0sc1 MALL reads.
    long long avail = (long long)ws_size - 4096;
    long long r = avail / (2LL * BH * 2);
    int R = (int)(r > NSTEPS ? NSTEPS : r);
    if (R < 2) R = 2;

    unsigned int* cnt = (unsigned int*)d_ws;
    unsigned short* h0b = (unsigned short*)((char*)d_ws + 4096);
    unsigned short* h1b = h0b + (size_t)R * BH;

    if (R >= 64)
        lstm_cached<<<dim3(256), dim3(256), LDS_BYTES, stream>>>(
            tokens, h0, c0, emb, Wih0, Whh0, bih0, bhh0, Wih1, Whh1, bih1, bhh1,
            (float*)d_out, h0b, h1b, cnt, R);
    else
        lstm_mall<<<dim3(256), dim3(256), LDS_BYTES, stream>>>(
            tokens, h0, c0, emb, Wih0, Whh0, bih0, bhh0, Wih1, Whh1, bih1, bhh1,
            (float*)d_out, h0b, h1b, cnt, R);
}

// Round 10
// 4599.020 us; speedup vs baseline: 1.9349x; 1.0502x over previous
//
#include <hip/hip_runtime.h>

// LSTM LM: S=512, B=32, H=D=1024, L=2 (fp32 tensors; bf16 MFMA compute).
// Persistent 2-team pipeline (A=layer0 blocks 0-127, B=layer1 blocks 128-255),
// weights LDS-resident. FINAL (= round-4 verified source, best: 4365us).
// Session conclusion: the kernel is LATENCY-floor-bound, not BW/compute-bound.
//  - MfmaUtil ~5%, HBM ~2% => neither pipe limits.
//  - Traffic experiments: MALL-read traffic x2 => time x2 (R7); /16 via
//    cached reads => no change (R9). Read path is not binding.
//  - Critical path: 512 serial steps x (publish drain to MALL + flag
//    propagation + poll RT + ~1.5us compute/sync) ~ 8.6us/step at
//    1 wave/SIMD (no TLP to hide stalls). All poll/barrier/cache-scope
//    variants land 4.4-4.9ms; per-step cache maintenance (R8) and
//    wave-autonomous restructure (R7) are strictly worse.

typedef __bf16 bf16x8 __attribute__((ext_vector_type(8)));
typedef float f32x4 __attribute__((ext_vector_type(4)));
typedef unsigned int u32x4 __attribute__((ext_vector_type(4)));

#define NSTEPS 512
#define TEAM   128
#define OUT_ELEMS 16777216   // 512*32*1024 fp32 outputs
#define BH 32768             // 32*1024

// LDS: wfrag 131072 | sc 18432 (128 x 36 f32) | bias 128 | cst 1024 | hst 512
#define LDS_BYTES 151168
#define OFF_SC   131072
#define OFF_BIAS 149504
#define OFF_CST  149632
#define OFF_HST  150656

__device__ __forceinline__ unsigned short f2b(float f) {
    unsigned int u = __float_as_uint(f);
    u += 0x7fffu + ((u >> 16) & 1u);   // RNE
    return (unsigned short)(u >> 16);
}
__device__ __forceinline__ float sigm(float x) { return 1.0f / (1.0f + __expf(-x)); }

__device__ __forceinline__ bf16x8 cvt8(const float* p) {
    float4 a = *(const float4*)p;
    float4 b = *(const float4*)(p + 4);
    bf16x8 r;
    r[0] = (__bf16)a.x; r[1] = (__bf16)a.y; r[2] = (__bf16)a.z; r[3] = (__bf16)a.w;
    r[4] = (__bf16)b.x; r[5] = (__bf16)b.y; r[6] = (__bf16)b.z; r[7] = (__bf16)b.w;
    return r;
}

// ---- coherence-point (MALL) access primitives ----
__device__ __forceinline__ bf16x8 ld_mall16(const unsigned short* p) {
    u32x4 r;
    asm volatile("global_load_dwordx4 %0, %1, off sc0 sc1" : "=v"(r) : "v"(p));
    return __builtin_bit_cast(bf16x8, r);
}
__device__ __forceinline__ void st_mall16(unsigned short* p, u32x4 v) {
    asm volatile("global_store_dwordx4 %0, %1, off sc0 sc1" :: "v"(p), "v"(v) : "memory");
}
__device__ __forceinline__ void st_mall2(unsigned short* p, unsigned int v) {
    asm volatile("global_store_short %0, %1, off sc0 sc1" :: "v"(p), "v"(v) : "memory");
}
__device__ __forceinline__ void wait_vm0() {
    asm volatile("s_waitcnt vmcnt(0)" ::: "memory");
}
__device__ __forceinline__ void wait_vm16() {
    asm volatile("s_waitcnt vmcnt(16)" ::: "memory");
}
__device__ __forceinline__ unsigned int flag_ld(const unsigned int* p) {
    return __hip_atomic_load(p, __ATOMIC_RELAXED, __HIP_MEMORY_SCOPE_AGENT);
}
__device__ __forceinline__ void flag_st(unsigned int* p, unsigned int v) {
    __hip_atomic_store(p, v, __ATOMIC_RELAXED, __HIP_MEMORY_SCOPE_AGENT);
}
// one wave covers 128 flags: lane handles f[lane] and f[64+lane]
__device__ __forceinline__ void poll2(const unsigned int* f, int lane, unsigned int tgt) {
    while (flag_ld(f + lane) < tgt) __builtin_amdgcn_s_sleep(1);
    while (flag_ld(f + 64 + lane) < tgt) __builtin_amdgcn_s_sleep(1);
}

extern "C" __global__ __launch_bounds__(256, 1)
void lstm_persist(const int* __restrict__ tokens,
                  const float* __restrict__ h0in,
                  const float* __restrict__ c0in,
                  const float* __restrict__ emb,
                  const float* __restrict__ Wih0,
                  const float* __restrict__ Whh0,
                  const float* __restrict__ bih0,
                  const float* __restrict__ bhh0,
                  const float* __restrict__ Wih1,
                  const float* __restrict__ Whh1,
                  const float* __restrict__ bih1,
                  const float* __restrict__ bhh1,
                  float* __restrict__ dout,
                  unsigned short* __restrict__ h0b,   // ring: R x BH bf16
                  unsigned short* __restrict__ h1b,   // ring: R x BH bf16
                  unsigned int* __restrict__ cnt,     // flagA[128], flagB[128]
                  int R)
{
    extern __shared__ char smem[];
    unsigned short* wfrag = (unsigned short*)smem;
    float* sc   = (float*)(smem + OFF_SC);
    float* bias = (float*)(smem + OFF_BIAS);
    float* cst  = (float*)(smem + OFF_CST);
    unsigned short* hst = (unsigned short*)(smem + OFF_HST);

    const int tid  = threadIdx.x;
    const int w    = tid >> 6;        // wave = K-quarter
    const int lane = tid & 63;
    const int lm   = lane & 15;
    const int lq   = lane >> 4;
    const int blk  = blockIdx.x;
    const bool tB  = (blk >= TEAM);   // teamB = layer 1
    const int bid  = tB ? blk - TEAM : blk;
    const int n0   = bid * 8;         // owned hidden units [n0, n0+8)

    const float* Wih = tB ? Wih1 : Wih0;
    const float* Whh = tB ? Whh1 : Whh0;
    const float* bi  = tB ? bih1 : bih0;
    const float* bh  = tB ? bhh1 : bhh0;
    unsigned int* flagA = cnt;
    unsigned int* flagB = cnt + TEAM;
    unsigned int* myflag = (tB ? flagB : flagA) + bid;

    // ---- initial h for OWN production region -> ring slot R-1 (write-through) ----
    {
        int u = tid & 7, b = tid >> 3;
        int loff = tB ? BH : 0;
        unsigned short v = f2b(h0in[loff + b * 1024 + n0 + u]);
        st_mall2((tB ? h1b : h0b) + (size_t)(R - 1) * BH + b * 1024 + n0 + u, (unsigned int)v);
    }

    // ---- convert owned weight columns fp32->bf16 into frag-ordered LDS ----
    // chunk = (mat*2+nt)*32+ks ; lane holds W[col nt*16+n][ks*32 + q*8 .. +7]
    for (int t = tid; t < 8192; t += 256) {
        int chunk = t >> 6; int l = t & 63;
        int mat = chunk >> 6; int rem = chunk & 63;
        int nt = rem >> 5; int ks = rem & 31;
        int n = l & 15, q = l >> 4;
        int cl = nt * 16 + n;
        int grow = (cl >> 3) * 1024 + n0 + (cl & 7);
        const float* src = (mat ? Whh : Wih) + (size_t)grow * 1024 + ks * 32 + q * 8;
        *(bf16x8*)(wfrag + chunk * 512 + l * 8) = cvt8(src);
    }
    if (tid < 32) {
        int grow = (tid >> 3) * 1024 + n0 + (tid & 7);
        bias[tid] = bi[grow] + bh[grow];
    }
    {   // fp32 cell state, block-resident
        int u = tid & 7, b = tid >> 3;
        int loff = tB ? BH : 0;
        cst[b * 8 + u] = c0in[loff + b * 1024 + n0 + u];
    }
    wait_vm0();          // drain asm init stores (outside compiler bookkeeping)
    __syncthreads();
    if (tid == 0) flag_st(myflag, 1u);   // flag==k  =>  h[k-2] published

    f32x4 acc[2][2];
    bf16x8 pre[2][8];
    bf16x8 sa[2][8];
    const f32x4 zero = {0.f, 0.f, 0.f, 0.f};

    for (int s = 0; s < NSTEPS; ++s) {
        const int slotPrev = (s + R - 1) % R;
        const int slotCur  = s % R;
        const unsigned short* hs;   // stream source (read at MALL)
        int preMat, strMat;

        if (!tB) {
            // ---- team A: emb gather (cached, broadcast token line) while peers finish ----
            #pragma unroll
            for (int mt = 0; mt < 2; ++mt) {
                const float* rowp = emb + (size_t)tokens[s * 32 + mt * 16 + lm] * 1024 + lq * 8;
                #pragma unroll
                for (int i = 0; i < 8; ++i)
                    pre[mt][i] = cvt8(rowp + (w * 8 + i) * 32);
            }
            // wave0: A peers done step s-1 ; wave1: back-pressure vs B at distance R
            if (w == 0)                   poll2(flagA, lane, (unsigned int)(s + 1));
            else if (w == 1 && s >= R)    poll2(flagB, lane, (unsigned int)(s - R + 2));
            __syncthreads();
            hs = h0b + (size_t)slotPrev * BH;  preMat = 0; strMat = 1;
        } else {
            // ---- team B: both conditions polled concurrently, one barrier ----
            if (w == 0)      poll2(flagB, lane, (unsigned int)(s + 1));
            else if (w == 1) poll2(flagA, lane, (unsigned int)(s + 2));
            __syncthreads();
            const unsigned short* h1src = h1b + (size_t)slotPrev * BH;
            #pragma unroll
            for (int mt = 0; mt < 2; ++mt)
                #pragma unroll
                for (int i = 0; i < 8; ++i)
                    pre[mt][i] = ld_mall16(h1src + (mt * 16 + lm) * 1024 + (w * 8 + i) * 32 + lq * 8);
            hs = h0b + (size_t)slotCur * BH;  preMat = 1; strMat = 0;
        }

        // ---- issue all stream fragments (MALL reads) ----
        #pragma unroll
        for (int mt = 0; mt < 2; ++mt)
            #pragma unroll
            for (int i = 0; i < 8; ++i)
                sa[mt][i] = ld_mall16(hs + (mt * 16 + lm) * 1024 + (w * 8 + i) * 32 + lq * 8);

        acc[0][0] = zero; acc[0][1] = zero; acc[1][0] = zero; acc[1][1] = zero;

        // B: wait only for the 16 pre (h1) loads; the 16 sa loads stay in flight.
        if (tB) { wait_vm16(); __builtin_amdgcn_sched_barrier(0); }

        // ---- pre half: MFMAs on pre operand while stream loads are in flight ----
        #pragma unroll
        for (int i = 0; i < 8; ++i) {
            int ks = w * 8 + i;
            bf16x8 bp0 = *(const bf16x8*)(wfrag + ((preMat * 2 + 0) * 32 + ks) * 512 + lane * 8);
            bf16x8 bp1 = *(const bf16x8*)(wfrag + ((preMat * 2 + 1) * 32 + ks) * 512 + lane * 8);
            acc[0][0] = __builtin_amdgcn_mfma_f32_16x16x32_bf16(pre[0][i], bp0, acc[0][0], 0, 0, 0);
            acc[0][1] = __builtin_amdgcn_mfma_f32_16x16x32_bf16(pre[0][i], bp1, acc[0][1], 0, 0, 0);
            acc[1][0] = __builtin_amdgcn_mfma_f32_16x16x32_bf16(pre[1][i], bp0, acc[1][0], 0, 0, 0);
            acc[1][1] = __builtin_amdgcn_mfma_f32_16x16x32_bf16(pre[1][i], bp1, acc[1][1], 0, 0, 0);
        }

        wait_vm0();
        __builtin_amdgcn_sched_barrier(0);

        // ---- stream half ----
        #pragma unroll
        for (int i = 0; i < 8; ++i) {
            int ks = w * 8 + i;
            bf16x8 bs0 = *(const bf16x8*)(wfrag + ((strMat * 2 + 0) * 32 + ks) * 512 + lane * 8);
            bf16x8 bs1 = *(const bf16x8*)(wfrag + ((strMat * 2 + 1) * 32 + ks) * 512 + lane * 8);
            acc[0][0] = __builtin_amdgcn_mfma_f32_16x16x32_bf16(sa[0][i], bs0, acc[0][0], 0, 0, 0);
            acc[0][1] = __builtin_amdgcn_mfma_f32_16x16x32_bf16(sa[0][i], bs1, acc[0][1], 0, 0, 0);
            acc[1][0] = __builtin_amdgcn_mfma_f32_16x16x32_bf16(sa[1][i], bs0, acc[1][0], 0, 0, 0);
            acc[1][1] = __builtin_amdgcn_mfma_f32_16x16x32_bf16(sa[1][i], bs1, acc[1][1], 0, 0, 0);
        }

        // cross-wave K reduction via padded LDS (C layout: col=lane&15, row=quad*4+reg)
        // pad 36: write 2-way, epilogue read bank=(4b+u)%32 -> 2-way (free)
        #pragma unroll
        for (int mt = 0; mt < 2; ++mt) {
            #pragma unroll
            for (int nt = 0; nt < 2; ++nt) {
                f32x4 a = acc[mt][nt];
                int col = nt * 16 + lm;
                int rb = w * 32 + mt * 16 + lq * 4;
                sc[(rb + 0) * 36 + col] = a[0];
                sc[(rb + 1) * 36 + col] = a[1];
                sc[(rb + 2) * 36 + col] = a[2];
                sc[(rb + 3) * 36 + col] = a[3];
            }
        }
        __syncthreads();

        // epilogue: gates -> (h,c) for owned 8 units x 32 batch
        {
            int u = tid & 7, b = tid >> 3;
            float G[4];
            #pragma unroll
            for (int g = 0; g < 4; ++g) {
                int col = g * 8 + u;
                float v = bias[col];
                #pragma unroll
                for (int w2 = 0; w2 < 4; ++w2) v += sc[(w2 * 32 + b) * 36 + col];
                G[g] = v;
            }
            float ig = sigm(G[0]);
            float fg = sigm(G[1]);
            float gg = tanhf(G[2]);
            float og = sigm(G[3]);
            float cOld = cst[b * 8 + u];
            float cNew = fg * cOld + ig * gg;
            float hNew = og * tanhf(cNew);
            cst[b * 8 + u] = cNew;
            hst[b * 8 + u] = f2b(hNew);
            __syncthreads();

            // wave0 publishes the whole 32x8 slice as 32 x 16B stores, drains
            // only its own wave, then flags. dout stores happen after the flag.
            if (tid < 32) {
                u32x4 v16 = *(const u32x4*)(hst + tid * 8);
                unsigned short* dst = (tB ? h1b : h0b) + (size_t)slotCur * BH + tid * 1024 + n0;
                st_mall16(dst, v16);
            }
            if (w == 0) {
                wait_vm0();
                if (tid == 0) flag_st(myflag, (unsigned int)(s + 2));
            }

            int off = b * 1024 + n0 + u;
            if (tB) {
                dout[(size_t)s * BH + off] = hNew;             // outputs [S,B,H]
                if (s == NSTEPS - 1) {
                    dout[OUT_ELEMS + BH + off] = hNew;         // hF layer1
                    dout[OUT_ELEMS + 3 * BH + off] = cNew;     // cF layer1
                }
            } else if (s == NSTEPS - 1) {
                dout[OUT_ELEMS + off] = hNew;                  // hF layer0
                dout[OUT_ELEMS + 2 * BH + off] = cNew;         // cF layer0
            }
        }
    }
}

extern "C" void kernel_launch(void* const* d_in, const int* in_sizes, int n_in,
                              void* d_out, int out_size, void* d_ws, size_t ws_size,
                              hipStream_t stream) {
    hipFuncSetAttribute((const void*)lstm_persist,
                        hipFuncAttributeMaxDynamicSharedMemorySize, LDS_BYTES);
    hipMemsetAsync(d_ws, 0, 4096, stream);   // flagA[128] + flagB[128] (+pad)

    const int* tokens = (const int*)d_in[0];
    const float* h0   = (const float*)d_in[1];
    const float* c0   = (const float*)d_in[2];
    const float* emb  = (const float*)d_in[3];
    const float* Wih0 = (const float*)d_in[4];
    const float* Whh0 = (const float*)d_in[5];
    const float* bih0 = (const float*)d_in[6];
    const float* bhh0 = (const float*)d_in[7];
    const float* Wih1 = (const float*)d_in[8];
    const float* Whh1 = (const float*)d_in[9];
    const float* bih1 = (const float*)d_in[10];
    const float* bhh1 = (const float*)d_in[11];

    // ring size from ws_size (constant across calls). Reuse is coherence-safe
    // at any R (MALL-through access); R only sets pipeline slack.
    long long avail = (long long)ws_size - 4096;
    long long r = avail / (2LL * BH * 2);
    int R = (int)(r > NSTEPS ? NSTEPS : r);
    if (R < 2) R = 2;

    unsigned int* cnt = (unsigned int*)d_ws;
    unsigned short* h0b = (unsigned short*)((char*)d_ws + 4096);
    unsigned short* h1b = h0b + (size_t)R * BH;

    lstm_persist<<<dim3(256), dim3(256), LDS_BYTES, stream>>>(
        tokens, h0, c0, emb, Wih0, Whh0, bih0, bhh0, Wih1, Whh1, bih1, bhh1,
        (float*)d_out, h0b, h1b, cnt, R);
}